// Round 5
// baseline (705.005 us; speedup 1.0000x reference)
//
#include <hip/hip_runtime.h>
#include <stdint.h>

// LSTM forward, MI355X. H=128, I=270, C=3, B=1024, T=270, NU=512, W rows 398.
//   pack_w (once): Wx->bf16 [512][288] padded, Wh->bf16 [512][128], bias fp32[512]
//   xp_gemm: xp = x@Wx^T + b, MFMA; fp32->bf16 conversion fused into reg-staging
//   lstm_scan: 256 blocks x 4 batch rows; recurrent MFMA; fused logits+softmax
// Round-5 change: single chunk (tc=270) -> one big dispatch per kernel so the
// scan/gemm show up in rocprof top-5 (diagnostic); c stays in registers for all
// 270 steps (no c_state round trip).

typedef __attribute__((ext_vector_type(8))) short short8;
typedef __attribute__((ext_vector_type(4))) float f32x4;
typedef __attribute__((ext_vector_type(2))) float f32x2;
typedef __attribute__((ext_vector_type(4))) unsigned int uint4v;
typedef unsigned short ush;

__device__ __forceinline__ ush f2bf(float f) {
    unsigned u = __float_as_uint(f);
    return (ush)((u + 0x7FFFu + ((u >> 16) & 1u)) >> 16);
}
__device__ __forceinline__ float bf2f(ush s) { return __uint_as_float(((unsigned)s) << 16); }
__device__ __forceinline__ float sigm_f(float x) {
    x = fminf(fmaxf(x, -30.f), 30.f);
    return 1.f / (1.f + __expf(-x));
}
__device__ __forceinline__ float tanh_f(float x) {
    x = fminf(fmaxf(x, -15.f), 15.f);
    float e = __expf(-2.f * x);
    return (1.f - e) / (1.f + e);
}
// Raw barrier: LDS visibility only; vmem ops stay outstanding (T4).
__device__ __forceinline__ void lds_barrier() {
    asm volatile("s_waitcnt lgkmcnt(0)" ::: "memory");
    __builtin_amdgcn_s_barrier();
    __builtin_amdgcn_sched_barrier(0);
    asm volatile("" ::: "memory");
}

// ---------------- pack_w ----------------
__global__ __launch_bounds__(256) void pack_w(
    const float* __restrict__ Wf, const float* __restrict__ Wi,
    const float* __restrict__ Wc, const float* __restrict__ Wo,
    const float* __restrict__ bf_, const float* __restrict__ bi_,
    const float* __restrict__ bc_, const float* __restrict__ bo_,
    ush* __restrict__ Wxp, ush* __restrict__ Whp, float* __restrict__ bpk)
{
    int idx = blockIdx.x * 256 + threadIdx.x;
    if (idx < 512 * 288) {
        int u = idx / 288, i = idx - u * 288;
        int g = u >> 7, j = u & 127;
        const float* Wg = (g == 0) ? Wf : (g == 1) ? Wi : (g == 2) ? Wc : Wo;
        float v = (i < 270) ? Wg[(size_t)j * 398 + 128 + i] : 0.f;
        Wxp[idx] = f2bf(v);
    }
    if (idx < 512 * 128) {
        int u = idx >> 7, k = idx & 127;
        int g = u >> 7, j = u & 127;
        const float* Wg = (g == 0) ? Wf : (g == 1) ? Wi : (g == 2) ? Wc : Wo;
        Whp[idx] = f2bf(Wg[(size_t)j * 398 + k]);
    }
    if (idx < 512) {
        int g = idx >> 7, j = idx & 127;
        const float* bg = (g == 0) ? bf_ : (g == 1) ? bi_ : (g == 2) ? bc_ : bo_;
        bpk[idx] = bg[j];
    }
}

// ---------------- xp_gemm: x fp32 -> (convert) -> MFMA -> xpc bf16 ----------------
// 256 thr = 4 waves (n-split). Tile 64 rows x 128 units, 3 m-tiles/block, K=288 (270
// real) in 9 steps of 32. Staging: thread loads 8 fp32, cvt_pk -> bf16x8, ds_write
// swizzled. Double-buffered LDS, 1 raw barrier/step, loads issued 2 steps ahead.
__global__ __launch_bounds__(256) void xp_gemm(
    const float* __restrict__ x, const ush* __restrict__ Wxp,
    const float* __restrict__ bpk, ush* __restrict__ xpc, int t0)
{
    __shared__ ush A_buf[2][64 * 32];
    const int tid = threadIdx.x;
    const int l = tid & 63, w = tid >> 6;     // w = wave_n
    const int l16 = l & 15, lq = l >> 4;
    const int blkN = blockIdx.y;
    const int row_base = blockIdx.x * 192;

    // B frags (bf16, L2-hot) + bias
    short8 bfrag[2][9]; float bias_v[2]; int ucol[2];
    #pragma unroll
    for (int nt = 0; nt < 2; ++nt) {
        int u = blkN * 128 + w * 32 + nt * 16 + l16;
        ucol[nt] = u; bias_v[nt] = bpk[u];
        const ush* bw = Wxp + (size_t)u * 288 + lq * 8;
        #pragma unroll
        for (int ks = 0; ks < 9; ++ks) bfrag[nt][ks] = *(const short8*)(bw + ks * 32);
    }

    // staging mapping: thread -> (row 0..63, 8-float group 0..3); XOR slot swizzle
    const int srow = tid >> 2, sgrp = tid & 3;
    const int pslot = sgrp ^ ((srow >> 1) & 3);
    const int wr_off = srow * 64 + pslot * 16;       // byte offset in A_buf[.]
    const float* srcb[3];
    #pragma unroll
    for (int mi = 0; mi < 3; ++mi) {
        int r = row_base + mi * 64 + srow;
        int tt = r >> 10, b = r & 1023;
        srcb[mi] = x + ((size_t)b * 270 + (size_t)(t0 + tt)) * 270 + sgrp * 8;
    }
    const int k0g8 = 256 + sgrp * 8;

    f32x4 acc[4][2];
    #pragma unroll
    for (int mt = 0; mt < 4; ++mt)
        #pragma unroll
        for (int nt = 0; nt < 2; ++nt)
            acc[mt][nt] = (f32x4){bias_v[nt], bias_v[nt], bias_v[nt], bias_v[nt]};

    f32x2 rA[4], rB[4];
    auto LOADX = [&](int s, f32x2 (&rr)[4]) {
        int mi = s / 9, ks = s - (s / 9) * 9;
        const float* p = srcb[mi] + ks * 32;
        if (ks < 8) {
            rr[0] = *(const f32x2*)p;       rr[1] = *(const f32x2*)(p + 2);
            rr[2] = *(const f32x2*)(p + 4); rr[3] = *(const f32x2*)(p + 6);
        } else {
            float tv[8];
            #pragma unroll
            for (int j = 0; j < 8; ++j) tv[j] = (k0g8 + j < 270) ? p[j] : 0.f;
            rr[0] = (f32x2){tv[0], tv[1]}; rr[1] = (f32x2){tv[2], tv[3]};
            rr[2] = (f32x2){tv[4], tv[5]}; rr[3] = (f32x2){tv[6], tv[7]};
        }
    };
    auto CVTW = [&](int s, f32x2 (&rr)[4]) {
        uint4v o;
        #pragma unroll
        for (int p = 0; p < 4; ++p) {
            unsigned v;
            asm("v_cvt_pk_bf16_f32 %0, %1, %2" : "=v"(v) : "v"(rr[p].x), "v"(rr[p].y));
            o[p] = v;
        }
        *(uint4v*)((char*)&A_buf[s & 1][0] + wr_off) = o;
    };

    LOADX(0, rA); CVTW(0, rA); LOADX(1, rB);
    lds_barrier();

    #pragma unroll
    for (int s = 0; s < 27; ++s) {
        const int mi = s / 9, ks = s - mi * 9;
        // A frags from buf[s&1] (swizzled slots -> 2-way banks, free)
        short8 afr[4];
        #pragma unroll
        for (int mt = 0; mt < 4; ++mt) {
            int boff = (mt * 16 + l16) * 64 + ((lq ^ ((l16 >> 1) & 3)) * 16);
            afr[mt] = *(const short8*)((const char*)&A_buf[s & 1][0] + boff);
        }
        if (s + 1 < 27) {
            if ((s + 1) & 1) CVTW(s + 1, rB); else CVTW(s + 1, rA);
            if (s + 2 < 27) { if ((s + 2) & 1) LOADX(s + 2, rB); else LOADX(s + 2, rA); }
        }
        // lgkmcnt(0): my afr reads + my ds_writes complete; staged global loads and
        // xpc stores stay in flight across the barrier.
        lds_barrier();
        #pragma unroll
        for (int mt = 0; mt < 4; ++mt)
            #pragma unroll
            for (int nt = 0; nt < 2; ++nt)
                acc[mt][nt] = __builtin_amdgcn_mfma_f32_16x16x32_bf16(
                    afr[mt], bfrag[nt][ks], acc[mt][nt], 0, 0, 0);
        if (ks == 8) {
            #pragma unroll
            for (int mt = 0; mt < 4; ++mt)
                #pragma unroll
                for (int nt = 0; nt < 2; ++nt) {
                    size_t rg = (size_t)row_base + mi * 64 + mt * 16 + lq * 4;
                    ush* dst = xpc + rg * 512 + ucol[nt];
                    #pragma unroll
                    for (int q = 0; q < 4; ++q) dst[q * 512] = f2bf(acc[mt][nt][q]);
                    acc[mt][nt] = (f32x4){bias_v[nt], bias_v[nt], bias_v[nt], bias_v[nt]};
                }
        }
    }
}

// ---------------- lstm_scan with fused logits+softmax ----------------
__global__ __launch_bounds__(512) void lstm_scan(
    const ush* __restrict__ xpc, const ush* __restrict__ Whp,
    float* __restrict__ c_state, float* __restrict__ out0, float* __restrict__ out1,
    const float* __restrict__ Wy, const float* __restrict__ by, int t0, int t1)
{
    __shared__ ush h_lds[2][16 * 128];
    __shared__ float part[2][4][8][3];
    const int tid = threadIdx.x;
    const int l = tid & 63, w = tid >> 6;
    const int l16 = l & 15, lq = l >> 4;
    const int b0 = blockIdx.x * 4;
    const int jcol = w * 16 + l16;

    short8 whf[4][4];
    #pragma unroll
    for (int g = 0; g < 4; ++g) {
        const ush* bw = Whp + ((size_t)(g * 128 + jcol)) * 128 + lq * 8;
        #pragma unroll
        for (int kf = 0; kf < 4; ++kf) whf[g][kf] = *(const short8*)(bw + kf * 32);
    }
    float wyr0 = Wy[jcol], wyr1 = Wy[128 + jcol], wyr2 = Wy[256 + jcol];
    float by0 = by[0], by1 = by[1], by2 = by[2];

    {   // zero both h buffers (rows 4..15 stay zero)
        ush* hp = &h_lds[0][0];
        for (int idx = tid; idx < 2 * 16 * 128; idx += 512) hp[idx] = 0;
    }
    __syncthreads();

    int cur = 0;
    float c1 = 0.f;
    if (t0 != 0) {
        c1 = c_state[(size_t)(b0 + lq) * 128 + jcol];
        int r = tid >> 7, k = tid & 127;
        float hv = out0[(size_t)(b0 + r) * (270 * 128) + (size_t)(t0 - 1) * 128 + k];
        int off = ((r * 128 + k) * 2) ^ ((r & 7) << 4);
        *(ush*)((char*)(&h_lds[0][0]) + off) = f2bf(hv);
        __syncthreads();
    }

    const ush* xp_base = xpc + ((size_t)(b0 + lq)) * 512 + jcol;
    ush P[4];
    #pragma unroll
    for (int g = 0; g < 4; ++g) P[g] = xp_base[g * 128];

    for (int t = t0; t < t1; ++t) {
        short8 afr[4];
        #pragma unroll
        for (int kf = 0; kf < 4; ++kf) {
            int off = ((l16 * 128 + kf * 32 + lq * 8) * 2) ^ ((l16 & 7) << 4);
            afr[kf] = *(const short8*)((const char*)(&h_lds[cur][0]) + off);
        }
        float xg[4];
        #pragma unroll
        for (int g = 0; g < 4; ++g) xg[g] = bf2f(P[g]);

        if (t + 1 < t1) {
            const ush* pn = xp_base + (size_t)(t + 1 - t0) * (1024 * 512);
            #pragma unroll
            for (int g = 0; g < 4; ++g) P[g] = pn[g * 128];
        }

        // split-K2: two independent chains per gate (depth 2) + add
        f32x4 a0_[4], a1_[4];
        #pragma unroll
        for (int g = 0; g < 4; ++g) {
            a0_[g] = (f32x4){0.f, 0.f, 0.f, 0.f};
            a1_[g] = (f32x4){0.f, 0.f, 0.f, 0.f};
        }
        #pragma unroll
        for (int g = 0; g < 4; ++g) {
            a0_[g] = __builtin_amdgcn_mfma_f32_16x16x32_bf16(afr[0], whf[g][0], a0_[g], 0, 0, 0);
            a1_[g] = __builtin_amdgcn_mfma_f32_16x16x32_bf16(afr[2], whf[g][2], a1_[g], 0, 0, 0);
            a0_[g] = __builtin_amdgcn_mfma_f32_16x16x32_bf16(afr[1], whf[g][1], a0_[g], 0, 0, 0);
            a1_[g] = __builtin_amdgcn_mfma_f32_16x16x32_bf16(afr[3], whf[g][3], a1_[g], 0, 0, 0);
        }

        // redistribute: lane takes reg q=lq from lane l16 -> full-wave gates
        float pre[4];
        #pragma unroll
        for (int g = 0; g < 4; ++g) {
            f32x4 accg = a0_[g] + a1_[g];
            float s0 = __shfl(accg[0], l16);
            float s1 = __shfl(accg[1], l16);
            float s2 = __shfl(accg[2], l16);
            float s3 = __shfl(accg[3], l16);
            float v = (lq == 0) ? s0 : (lq == 1) ? s1 : (lq == 2) ? s2 : s3;
            pre[g] = v + xg[g];
        }
        float fg = sigm_f(pre[0]);
        float ig = sigm_f(pre[1]);
        float gg = tanh_f(pre[2]);
        float og = sigm_f(pre[3]);
        float cn = fg * c1 + ig * gg;
        c1 = cn;
        float hv = og * tanh_f(cn);
        {
            int off = ((lq * 128 + jcol) * 2) ^ ((lq & 7) << 4);
            *(ush*)((char*)(&h_lds[cur ^ 1][0]) + off) = f2bf(hv);
        }
        // fused logits partials: reduce h*Wy over this wave's 16-unit slice
        float p0 = hv * wyr0, p1 = hv * wyr1, p2 = hv * wyr2;
        #pragma unroll
        for (int d = 1; d < 16; d <<= 1) {
            p0 += __shfl_xor(p0, d);
            p1 += __shfl_xor(p1, d);
            p2 += __shfl_xor(p2, d);
        }
        if (l16 == 0) {
            float* pp = &part[t & 1][lq][w][0];
            pp[0] = p0; pp[1] = p1; pp[2] = p2;
        }
        // out0 store: fire-and-forget (never drained by the raw barrier)
        out0[(size_t)(b0 + lq) * (270 * 128) + (size_t)t * 128 + jcol] = hv;

        // lgkmcnt(0): h/part writes + afr/part reads complete; out0 store and P
        // prefetch stay in flight.
        lds_barrier();

        // softmax finish (reads part[t&1]; next step writes part[(t+1)&1])
        if (tid < 4) {
            const float* pr = &part[t & 1][tid][0][0];
            float L0 = by0, L1 = by1, L2 = by2;
            #pragma unroll
            for (int ww = 0; ww < 8; ++ww) {
                L0 += pr[ww * 3]; L1 += pr[ww * 3 + 1]; L2 += pr[ww * 3 + 2];
            }
            float m = fmaxf(L0, fmaxf(L1, L2));
            float e0 = __expf(L0 - m), e1 = __expf(L1 - m), e2 = __expf(L2 - m);
            float inv = 1.f / (e0 + e1 + e2);
            float* o = out1 + ((size_t)(b0 + tid) * 270 + t) * 3;
            o[0] = e0 * inv; o[1] = e1 * inv; o[2] = e2 * inv;
        }
        cur ^= 1;
    }
    if (t1 != 270)
        c_state[(size_t)(b0 + lq) * 128 + jcol] = c1;
}

// ---------------- host ----------------
extern "C" void kernel_launch(void* const* d_in, const int* in_sizes, int n_in,
                              void* d_out, int out_size, void* d_ws, size_t ws_size,
                              hipStream_t stream) {
    (void)in_sizes; (void)n_in; (void)out_size;
    const float* x   = (const float*)d_in[0];
    const float* Wf  = (const float*)d_in[1];
    const float* Wi  = (const float*)d_in[2];
    const float* Wc  = (const float*)d_in[3];
    const float* Wo  = (const float*)d_in[4];
    const float* Wy  = (const float*)d_in[5];
    const float* bfp = (const float*)d_in[6];
    const float* bip = (const float*)d_in[7];
    const float* bcp = (const float*)d_in[8];
    const float* bop = (const float*)d_in[9];
    const float* byp = (const float*)d_in[10];

    float* out0 = (float*)d_out;                       // [B,T,H]
    float* out1 = out0 + (size_t)1024 * 270 * 128;     // [B,T,3]

    long tc = 6;
    {
        const long cand[6] = {270, 90, 54, 30, 18, 6};
        for (int i = 0; i < 6; ++i) {
            size_t need = (size_t)cand[i] * 1048576u + (2u << 20);
            if (need <= ws_size) { tc = cand[i]; break; }
        }
    }
    char* wsb = (char*)d_ws;
    ush* xpc = (ush*)wsb;                              // tc MB
    char* fx = wsb + (size_t)tc * 1048576u;
    float* c_state = (float*)fx;                       // 512 KB
    ush* Wxp = (ush*)(fx + 524288);                    // 288 KB
    ush* Whp = (ush*)(fx + 524288 + 294912);           // 128 KB
    float* bpk = (float*)(fx + 524288 + 294912 + 131072);

    pack_w<<<576, 256, 0, stream>>>(Wf, Wi, Wc, Wo, bfp, bip, bcp, bop, Wxp, Whp, bpk);

    for (int t0 = 0; t0 < 270; t0 += (int)tc) {
        int Tcur = (270 - t0) < (int)tc ? (270 - t0) : (int)tc;
        int rows = Tcur * 1024;
        dim3 g(rows / 192, 4);
        xp_gemm<<<g, 256, 0, stream>>>(x, Wxp, bpk, xpc, t0);
        lstm_scan<<<256, 512, 0, stream>>>(xpc, Whp, c_state, out0, out1, Wy, byp,
                                           t0, t0 + Tcur);
    }
}

// Round 6
// 642.811 us; speedup vs baseline: 1.0968x; 1.0968x over previous
//
#include <hip/hip_runtime.h>
#include <stdint.h>

// LSTM forward, MI355X. H=128, I=270, C=3, B=1024, T=270, NU=512, W rows 398.
//   pack_w (once): Wx->bf16 [512][288] padded, Wh->bf16 [512][128], bias fp32[512]
//   xp_gemm: 64-row x 512-unit block tile; x read ONCE; A staged once in LDS;
//            barrier-free K-loop with ping-pong B prefetch from L2-hot Wxp.
//   lstm_scan: 256 blocks x 4 batch rows; recurrent MFMA; fused logits+softmax;
//            xp prefetch depth 2 (hides HBM latency of the xpc stream).

typedef __attribute__((ext_vector_type(8))) short short8;
typedef __attribute__((ext_vector_type(4))) float f32x4;
typedef __attribute__((ext_vector_type(2))) float f32x2;
typedef __attribute__((ext_vector_type(4))) unsigned int uint4v;
typedef unsigned short ush;

__device__ __forceinline__ ush f2bf(float f) {
    unsigned u = __float_as_uint(f);
    return (ush)((u + 0x7FFFu + ((u >> 16) & 1u)) >> 16);
}
__device__ __forceinline__ float bf2f(ush s) { return __uint_as_float(((unsigned)s) << 16); }
__device__ __forceinline__ float sigm_f(float x) {
    x = fminf(fmaxf(x, -30.f), 30.f);
    return 1.f / (1.f + __expf(-x));
}
__device__ __forceinline__ float tanh_f(float x) {
    x = fminf(fmaxf(x, -15.f), 15.f);
    float e = __expf(-2.f * x);
    return (1.f - e) / (1.f + e);
}
// Raw barrier: LDS visibility only; vmem ops stay outstanding (T4).
__device__ __forceinline__ void lds_barrier() {
    asm volatile("s_waitcnt lgkmcnt(0)" ::: "memory");
    __builtin_amdgcn_s_barrier();
    __builtin_amdgcn_sched_barrier(0);
    asm volatile("" ::: "memory");
}

// ---------------- pack_w ----------------
__global__ __launch_bounds__(256) void pack_w(
    const float* __restrict__ Wf, const float* __restrict__ Wi,
    const float* __restrict__ Wc, const float* __restrict__ Wo,
    const float* __restrict__ bf_, const float* __restrict__ bi_,
    const float* __restrict__ bc_, const float* __restrict__ bo_,
    ush* __restrict__ Wxp, ush* __restrict__ Whp, float* __restrict__ bpk)
{
    int idx = blockIdx.x * 256 + threadIdx.x;
    if (idx < 512 * 288) {
        int u = idx / 288, i = idx - u * 288;
        int g = u >> 7, j = u & 127;
        const float* Wg = (g == 0) ? Wf : (g == 1) ? Wi : (g == 2) ? Wc : Wo;
        float v = (i < 270) ? Wg[(size_t)j * 398 + 128 + i] : 0.f;
        Wxp[idx] = f2bf(v);
    }
    if (idx < 512 * 128) {
        int u = idx >> 7, k = idx & 127;
        int g = u >> 7, j = u & 127;
        const float* Wg = (g == 0) ? Wf : (g == 1) ? Wi : (g == 2) ? Wc : Wo;
        Whp[idx] = f2bf(Wg[(size_t)j * 398 + k]);
    }
    if (idx < 512) {
        int g = idx >> 7, j = idx & 127;
        const float* bg = (g == 0) ? bf_ : (g == 1) ? bi_ : (g == 2) ? bc_ : bo_;
        bpk[idx] = bg[j];
    }
}

// ---------------- xp_gemm v2: x read once ----------------
// Block: 64 rows x 512 units (ALL units -> no x re-read). 256 thr = 4 waves,
// wave w owns units [w*128, w*128+128) as 8 n-tiles. K=288 in 9 steps.
// A staged once (36 loads issued up front -> cvt_pk -> ds_write, ONE barrier),
// then barrier-free K-loop: ping-pong B-frag prefetch + 4 ds_read + 32 MFMA.
__global__ __launch_bounds__(256, 2) void xp_gemm(
    const float* __restrict__ x, const ush* __restrict__ Wxp,
    const float* __restrict__ bpk, ush* __restrict__ xpc, int t0)
{
    __shared__ ush A_lds[64 * 296];                 // stride 296 elem -> 2-way banks
    const int tid = threadIdx.x;
    const int l = tid & 63, w = tid >> 6;
    const int l16 = l & 15, lq = l >> 4;
    const size_t row0 = (size_t)blockIdx.x * 64;

    // ---- issue all A loads (fp32) ----
    const int srow = tid >> 2, sgrp = tid & 3;      // row 0..63, 8-col group 0..3
    {
    }
    const int r = (int)row0 + srow;
    const int b = r & 1023, tt = (r >> 10) + t0;
    const float* xrow = x + ((size_t)b * 270 + tt) * 270;
    f32x2 stg[9][4];
    #pragma unroll
    for (int ks = 0; ks < 9; ++ks) {
        const int col = ks * 32 + sgrp * 8;
        const float* p = xrow + col;
        if (col + 8 <= 270) {
            stg[ks][0] = *(const f32x2*)p;       stg[ks][1] = *(const f32x2*)(p + 2);
            stg[ks][2] = *(const f32x2*)(p + 4); stg[ks][3] = *(const f32x2*)(p + 6);
        } else {
            float tv[8];
            #pragma unroll
            for (int j = 0; j < 8; ++j) tv[j] = (col + j < 270) ? p[j] : 0.f;
            stg[ks][0] = (f32x2){tv[0], tv[1]}; stg[ks][1] = (f32x2){tv[2], tv[3]};
            stg[ks][2] = (f32x2){tv[4], tv[5]}; stg[ks][3] = (f32x2){tv[6], tv[7]};
        }
    }

    // ---- B-frag base + prefetch ks=0 set; bias ----
    const ush* bptr = Wxp + ((size_t)(w * 128 + l16)) * 288 + lq * 8;
    short8 bA[8], bB[8];
    #pragma unroll
    for (int nt = 0; nt < 8; ++nt) bA[nt] = *(const short8*)(bptr + nt * 4608);
    float bias_v[8];
    #pragma unroll
    for (int nt = 0; nt < 8; ++nt) bias_v[nt] = bpk[w * 128 + nt * 16 + l16];

    // ---- convert + LDS write, one barrier ----
    {
        ush* wrow = &A_lds[srow * 296 + sgrp * 8];
        #pragma unroll
        for (int ks = 0; ks < 9; ++ks) {
            uint4v o;
            #pragma unroll
            for (int p2 = 0; p2 < 4; ++p2) {
                unsigned v;
                asm("v_cvt_pk_bf16_f32 %0, %1, %2"
                    : "=v"(v) : "v"(stg[ks][p2].x), "v"(stg[ks][p2].y));
                o[p2] = v;
            }
            *(uint4v*)(wrow + ks * 32) = o;
        }
    }
    lds_barrier();                                  // bA loads stay in flight

    f32x4 acc[4][8];
    #pragma unroll
    for (int mt = 0; mt < 4; ++mt)
        #pragma unroll
        for (int nt = 0; nt < 8; ++nt)
            acc[mt][nt] = (f32x4){bias_v[nt], bias_v[nt], bias_v[nt], bias_v[nt]};

    // ---- barrier-free K-loop ----
    #pragma unroll
    for (int ks = 0; ks < 9; ++ks) {
        short8* cur = (ks & 1) ? bB : bA;
        short8* nxt = (ks & 1) ? bA : bB;
        if (ks + 1 < 9) {
            const ush* np = bptr + (ks + 1) * 32;
            #pragma unroll
            for (int nt = 0; nt < 8; ++nt) nxt[nt] = *(const short8*)(np + nt * 4608);
        }
        short8 afr[4];
        #pragma unroll
        for (int mt = 0; mt < 4; ++mt)
            afr[mt] = *(const short8*)(&A_lds[(mt * 16 + l16) * 296 + ks * 32 + lq * 8]);
        #pragma unroll
        for (int mt = 0; mt < 4; ++mt)
            #pragma unroll
            for (int nt = 0; nt < 8; ++nt)
                acc[mt][nt] = __builtin_amdgcn_mfma_f32_16x16x32_bf16(
                    afr[mt], cur[nt], acc[mt][nt], 0, 0, 0);
    }

    // ---- store (bf16, 2B scattered; WRITE_SIZE showed no amplification) ----
    #pragma unroll
    for (int mt = 0; mt < 4; ++mt)
        #pragma unroll
        for (int nt = 0; nt < 8; ++nt) {
            size_t rg = row0 + mt * 16 + lq * 4;
            ush* dst = xpc + rg * 512 + w * 128 + nt * 16 + l16;
            #pragma unroll
            for (int q = 0; q < 4; ++q) dst[q * 512] = f2bf(acc[mt][nt][q]);
        }
}

// ---------------- lstm_scan with fused logits+softmax ----------------
__global__ __launch_bounds__(512) void lstm_scan(
    const ush* __restrict__ xpc, const ush* __restrict__ Whp,
    float* __restrict__ c_state, float* __restrict__ out0, float* __restrict__ out1,
    const float* __restrict__ Wy, const float* __restrict__ by, int t0, int t1)
{
    __shared__ ush h_lds[2][16 * 128];
    __shared__ float part[2][4][8][3];
    const int tid = threadIdx.x;
    const int l = tid & 63, w = tid >> 6;
    const int l16 = l & 15, lq = l >> 4;
    const int b0 = blockIdx.x * 4;
    const int jcol = w * 16 + l16;

    short8 whf[4][4];
    #pragma unroll
    for (int g = 0; g < 4; ++g) {
        const ush* bw = Whp + ((size_t)(g * 128 + jcol)) * 128 + lq * 8;
        #pragma unroll
        for (int kf = 0; kf < 4; ++kf) whf[g][kf] = *(const short8*)(bw + kf * 32);
    }
    float wyr0 = Wy[jcol], wyr1 = Wy[128 + jcol], wyr2 = Wy[256 + jcol];
    float by0 = by[0], by1 = by[1], by2 = by[2];

    {   // zero both h buffers (rows 4..15 stay zero)
        ush* hp = &h_lds[0][0];
        for (int idx = tid; idx < 2 * 16 * 128; idx += 512) hp[idx] = 0;
    }
    __syncthreads();

    int cur = 0;
    float c1 = 0.f;
    if (t0 != 0) {
        c1 = c_state[(size_t)(b0 + lq) * 128 + jcol];
        int r = tid >> 7, k = tid & 127;
        float hv = out0[(size_t)(b0 + r) * (270 * 128) + (size_t)(t0 - 1) * 128 + k];
        int off = ((r * 128 + k) * 2) ^ ((r & 7) << 4);
        *(ush*)((char*)(&h_lds[0][0]) + off) = f2bf(hv);
        __syncthreads();
    }

    const ush* xp_base = xpc + ((size_t)(b0 + lq)) * 512 + jcol;
    // prefetch depth 2: Pa holds t, Pb holds t+1; reload consumed set with t+2
    ush Pa[4], Pb[4];
    #pragma unroll
    for (int g = 0; g < 4; ++g) Pa[g] = xp_base[g * 128];
    {
        const ush* pn = xp_base + (size_t)1 * (1024 * 512);
        #pragma unroll
        for (int g = 0; g < 4; ++g) Pb[g] = pn[g * 128];
    }

    auto STEP = [&](int t, ush (&Pu)[4]) {
        short8 afr[4];
        #pragma unroll
        for (int kf = 0; kf < 4; ++kf) {
            int off = ((l16 * 128 + kf * 32 + lq * 8) * 2) ^ ((l16 & 7) << 4);
            afr[kf] = *(const short8*)((const char*)(&h_lds[cur][0]) + off);
        }
        float xg[4];
        #pragma unroll
        for (int g = 0; g < 4; ++g) xg[g] = bf2f(Pu[g]);

        if (t + 2 < t1) {                 // reload freed set for t+2
            const ush* pn = xp_base + (size_t)(t + 2 - t0) * (1024 * 512);
            #pragma unroll
            for (int g = 0; g < 4; ++g) Pu[g] = pn[g * 128];
        }

        // split-K2: two independent chains per gate (depth 2) + add
        f32x4 a0_[4], a1_[4];
        #pragma unroll
        for (int g = 0; g < 4; ++g) {
            a0_[g] = (f32x4){0.f, 0.f, 0.f, 0.f};
            a1_[g] = (f32x4){0.f, 0.f, 0.f, 0.f};
        }
        #pragma unroll
        for (int g = 0; g < 4; ++g) {
            a0_[g] = __builtin_amdgcn_mfma_f32_16x16x32_bf16(afr[0], whf[g][0], a0_[g], 0, 0, 0);
            a1_[g] = __builtin_amdgcn_mfma_f32_16x16x32_bf16(afr[2], whf[g][2], a1_[g], 0, 0, 0);
            a0_[g] = __builtin_amdgcn_mfma_f32_16x16x32_bf16(afr[1], whf[g][1], a0_[g], 0, 0, 0);
            a1_[g] = __builtin_amdgcn_mfma_f32_16x16x32_bf16(afr[3], whf[g][3], a1_[g], 0, 0, 0);
        }

        // redistribute: lane takes reg q=lq from lane l16 -> full-wave gates
        float pre[4];
        #pragma unroll
        for (int g = 0; g < 4; ++g) {
            f32x4 accg = a0_[g] + a1_[g];
            float s0 = __shfl(accg[0], l16);
            float s1 = __shfl(accg[1], l16);
            float s2 = __shfl(accg[2], l16);
            float s3 = __shfl(accg[3], l16);
            float v = (lq == 0) ? s0 : (lq == 1) ? s1 : (lq == 2) ? s2 : s3;
            pre[g] = v + xg[g];
        }
        float fg = sigm_f(pre[0]);
        float ig = sigm_f(pre[1]);
        float gg = tanh_f(pre[2]);
        float og = sigm_f(pre[3]);
        float cn = fg * c1 + ig * gg;
        c1 = cn;
        float hv = og * tanh_f(cn);
        {
            int off = ((lq * 128 + jcol) * 2) ^ ((lq & 7) << 4);
            *(ush*)((char*)(&h_lds[cur ^ 1][0]) + off) = f2bf(hv);
        }
        // fused logits partials over this wave's 16-unit slice
        float p0 = hv * wyr0, p1 = hv * wyr1, p2 = hv * wyr2;
        #pragma unroll
        for (int d = 1; d < 16; d <<= 1) {
            p0 += __shfl_xor(p0, d);
            p1 += __shfl_xor(p1, d);
            p2 += __shfl_xor(p2, d);
        }
        if (l16 == 0) {
            float* pp = &part[t & 1][lq][w][0];
            pp[0] = p0; pp[1] = p1; pp[2] = p2;
        }
        // out0 store: fire-and-forget (never drained by the raw barrier)
        out0[(size_t)(b0 + lq) * (270 * 128) + (size_t)t * 128 + jcol] = hv;

        lds_barrier();

        // softmax finish (reads part[t&1]; next step writes part[(t+1)&1])
        if (tid < 4) {
            const float* pr = &part[t & 1][tid][0][0];
            float L0 = by0, L1 = by1, L2 = by2;
            #pragma unroll
            for (int ww = 0; ww < 8; ++ww) {
                L0 += pr[ww * 3]; L1 += pr[ww * 3 + 1]; L2 += pr[ww * 3 + 2];
            }
            float m = fmaxf(L0, fmaxf(L1, L2));
            float e0 = __expf(L0 - m), e1 = __expf(L1 - m), e2 = __expf(L2 - m);
            float inv = 1.f / (e0 + e1 + e2);
            float* o = out1 + ((size_t)(b0 + tid) * 270 + t) * 3;
            o[0] = e0 * inv; o[1] = e1 * inv; o[2] = e2 * inv;
        }
        cur ^= 1;
    };

    for (int t = t0; t < t1; t += 2) {    // (t1-t0) is always even
        STEP(t, Pa);
        STEP(t + 1, Pb);
    }
    if (t1 != 270)
        c_state[(size_t)(b0 + lq) * 128 + jcol] = c1;
}

// ---------------- host ----------------
extern "C" void kernel_launch(void* const* d_in, const int* in_sizes, int n_in,
                              void* d_out, int out_size, void* d_ws, size_t ws_size,
                              hipStream_t stream) {
    (void)in_sizes; (void)n_in; (void)out_size;
    const float* x   = (const float*)d_in[0];
    const float* Wf  = (const float*)d_in[1];
    const float* Wi  = (const float*)d_in[2];
    const float* Wc  = (const float*)d_in[3];
    const float* Wo  = (const float*)d_in[4];
    const float* Wy  = (const float*)d_in[5];
    const float* bfp = (const float*)d_in[6];
    const float* bip = (const float*)d_in[7];
    const float* bcp = (const float*)d_in[8];
    const float* bop = (const float*)d_in[9];
    const float* byp = (const float*)d_in[10];

    float* out0 = (float*)d_out;                       // [B,T,H]
    float* out1 = out0 + (size_t)1024 * 270 * 128;     // [B,T,3]

    long tc = 6;
    {
        const long cand[6] = {270, 90, 54, 30, 18, 6};
        for (int i = 0; i < 6; ++i) {
            size_t need = (size_t)cand[i] * 1048576u + (2u << 20);
            if (need <= ws_size) { tc = cand[i]; break; }
        }
    }
    char* wsb = (char*)d_ws;
    ush* xpc = (ush*)wsb;                              // tc MB
    char* fx = wsb + (size_t)tc * 1048576u;
    float* c_state = (float*)fx;                       // 512 KB
    ush* Wxp = (ush*)(fx + 524288);                    // 288 KB
    ush* Whp = (ush*)(fx + 524288 + 294912);           // 128 KB
    float* bpk = (float*)(fx + 524288 + 294912 + 131072);

    pack_w<<<576, 256, 0, stream>>>(Wf, Wi, Wc, Wo, bfp, bip, bcp, bop, Wxp, Whp, bpk);

    for (int t0 = 0; t0 < 270; t0 += (int)tc) {
        int Tcur = (270 - t0) < (int)tc ? (270 - t0) : (int)tc;
        int rows = Tcur * 1024;
        xp_gemm<<<rows / 64, 256, 0, stream>>>(x, Wxp, bpk, xpc, t0);
        lstm_scan<<<256, 512, 0, stream>>>(xpc, Whp, c_state, out0, out1, Wy, byp,
                                           t0, t0 + Tcur);
    }
}

// Round 7
// 642.283 us; speedup vs baseline: 1.0977x; 1.0008x over previous
//
#include <hip/hip_runtime.h>
#include <stdint.h>

// LSTM forward, MI355X. H=128, I=270, C=3, B=1024, T=270, NU=512, W rows 398.
//   pack_w (once): Wx->bf16 [512][288] padded, Wh->bf16 [512][128], bias fp32[512]
//   xp_gemm: 64-row x 512-unit block tile; x read ONCE; A staged once in LDS;
//            barrier-free K-loop with ping-pong B prefetch from L2-hot Wxp.
//   lstm_scan: 256 blocks x 4 batch rows; recurrent MFMA; fused logits+softmax;
//            xp prefetch depth 2 (hides HBM latency of the xpc stream).

typedef __attribute__((ext_vector_type(8))) short short8;
typedef __attribute__((ext_vector_type(4))) float f32x4;
typedef __attribute__((ext_vector_type(2))) float f32x2;
typedef __attribute__((ext_vector_type(4))) unsigned int uint4v;
typedef unsigned short ush;

__device__ __forceinline__ ush f2bf(float f) {
    unsigned u = __float_as_uint(f);
    return (ush)((u + 0x7FFFu + ((u >> 16) & 1u)) >> 16);
}
__device__ __forceinline__ float bf2f(ush s) { return __uint_as_float(((unsigned)s) << 16); }
__device__ __forceinline__ float sigm_f(float x) {
    x = fminf(fmaxf(x, -30.f), 30.f);
    return 1.f / (1.f + __expf(-x));
}
__device__ __forceinline__ float tanh_f(float x) {
    x = fminf(fmaxf(x, -15.f), 15.f);
    float e = __expf(-2.f * x);
    return (1.f - e) / (1.f + e);
}
// Raw barrier: LDS visibility only; vmem ops stay outstanding (T4).
__device__ __forceinline__ void lds_barrier() {
    asm volatile("s_waitcnt lgkmcnt(0)" ::: "memory");
    __builtin_amdgcn_s_barrier();
    __builtin_amdgcn_sched_barrier(0);
    asm volatile("" ::: "memory");
}

// ---------------- pack_w ----------------
__global__ __launch_bounds__(256) void pack_w(
    const float* __restrict__ Wf, const float* __restrict__ Wi,
    const float* __restrict__ Wc, const float* __restrict__ Wo,
    const float* __restrict__ bf_, const float* __restrict__ bi_,
    const float* __restrict__ bc_, const float* __restrict__ bo_,
    ush* __restrict__ Wxp, ush* __restrict__ Whp, float* __restrict__ bpk)
{
    int idx = blockIdx.x * 256 + threadIdx.x;
    if (idx < 512 * 288) {
        int u = idx / 288, i = idx - u * 288;
        int g = u >> 7, j = u & 127;
        const float* Wg = (g == 0) ? Wf : (g == 1) ? Wi : (g == 2) ? Wc : Wo;
        float v = (i < 270) ? Wg[(size_t)j * 398 + 128 + i] : 0.f;
        Wxp[idx] = f2bf(v);
    }
    if (idx < 512 * 128) {
        int u = idx >> 7, k = idx & 127;
        int g = u >> 7, j = u & 127;
        const float* Wg = (g == 0) ? Wf : (g == 1) ? Wi : (g == 2) ? Wc : Wo;
        Whp[idx] = f2bf(Wg[(size_t)j * 398 + k]);
    }
    if (idx < 512) {
        int g = idx >> 7, j = idx & 127;
        const float* bg = (g == 0) ? bf_ : (g == 1) ? bi_ : (g == 2) ? bc_ : bo_;
        bpk[idx] = bg[j];
    }
}

// ---------------- xp_gemm v2: x read once ----------------
// Block: 64 rows x 512 units (ALL units -> no x re-read). 256 thr = 4 waves,
// wave w owns units [w*128, w*128+128) as 8 n-tiles. K=288 in 9 steps.
// A staged once (36 loads issued up front -> cvt_pk -> ds_write, ONE barrier),
// then barrier-free K-loop: ping-pong B-frag prefetch + 4 ds_read + 32 MFMA.
__global__ __launch_bounds__(256, 2) void xp_gemm(
    const float* __restrict__ x, const ush* __restrict__ Wxp,
    const float* __restrict__ bpk, ush* __restrict__ xpc, int t0)
{
    __shared__ ush A_lds[64 * 296];                 // stride 296 elem -> 2-way banks
    const int tid = threadIdx.x;
    const int l = tid & 63, w = tid >> 6;
    const int l16 = l & 15, lq = l >> 4;
    const size_t row0 = (size_t)blockIdx.x * 64;

    // ---- issue all A loads (fp32) ----
    const int srow = tid >> 2, sgrp = tid & 3;      // row 0..63, 8-col group 0..3
    {
    }
    const int r = (int)row0 + srow;
    const int b = r & 1023, tt = (r >> 10) + t0;
    const float* xrow = x + ((size_t)b * 270 + tt) * 270;
    f32x2 stg[9][4];
    #pragma unroll
    for (int ks = 0; ks < 9; ++ks) {
        const int col = ks * 32 + sgrp * 8;
        const float* p = xrow + col;
        if (col + 8 <= 270) {
            stg[ks][0] = *(const f32x2*)p;       stg[ks][1] = *(const f32x2*)(p + 2);
            stg[ks][2] = *(const f32x2*)(p + 4); stg[ks][3] = *(const f32x2*)(p + 6);
        } else {
            float tv[8];
            #pragma unroll
            for (int j = 0; j < 8; ++j) tv[j] = (col + j < 270) ? p[j] : 0.f;
            stg[ks][0] = (f32x2){tv[0], tv[1]}; stg[ks][1] = (f32x2){tv[2], tv[3]};
            stg[ks][2] = (f32x2){tv[4], tv[5]}; stg[ks][3] = (f32x2){tv[6], tv[7]};
        }
    }

    // ---- B-frag base + prefetch ks=0 set; bias ----
    const ush* bptr = Wxp + ((size_t)(w * 128 + l16)) * 288 + lq * 8;
    short8 bA[8], bB[8];
    #pragma unroll
    for (int nt = 0; nt < 8; ++nt) bA[nt] = *(const short8*)(bptr + nt * 4608);
    float bias_v[8];
    #pragma unroll
    for (int nt = 0; nt < 8; ++nt) bias_v[nt] = bpk[w * 128 + nt * 16 + l16];

    // ---- convert + LDS write, one barrier ----
    {
        ush* wrow = &A_lds[srow * 296 + sgrp * 8];
        #pragma unroll
        for (int ks = 0; ks < 9; ++ks) {
            uint4v o;
            #pragma unroll
            for (int p2 = 0; p2 < 4; ++p2) {
                unsigned v;
                asm("v_cvt_pk_bf16_f32 %0, %1, %2"
                    : "=v"(v) : "v"(stg[ks][p2].x), "v"(stg[ks][p2].y));
                o[p2] = v;
            }
            *(uint4v*)(wrow + ks * 32) = o;
        }
    }
    lds_barrier();                                  // bA loads stay in flight

    f32x4 acc[4][8];
    #pragma unroll
    for (int mt = 0; mt < 4; ++mt)
        #pragma unroll
        for (int nt = 0; nt < 8; ++nt)
            acc[mt][nt] = (f32x4){bias_v[nt], bias_v[nt], bias_v[nt], bias_v[nt]};

    // ---- barrier-free K-loop ----
    #pragma unroll
    for (int ks = 0; ks < 9; ++ks) {
        short8* cur = (ks & 1) ? bB : bA;
        short8* nxt = (ks & 1) ? bA : bB;
        if (ks + 1 < 9) {
            const ush* np = bptr + (ks + 1) * 32;
            #pragma unroll
            for (int nt = 0; nt < 8; ++nt) nxt[nt] = *(const short8*)(np + nt * 4608);
        }
        short8 afr[4];
        #pragma unroll
        for (int mt = 0; mt < 4; ++mt)
            afr[mt] = *(const short8*)(&A_lds[(mt * 16 + l16) * 296 + ks * 32 + lq * 8]);
        #pragma unroll
        for (int mt = 0; mt < 4; ++mt)
            #pragma unroll
            for (int nt = 0; nt < 8; ++nt)
                acc[mt][nt] = __builtin_amdgcn_mfma_f32_16x16x32_bf16(
                    afr[mt], cur[nt], acc[mt][nt], 0, 0, 0);
    }

    // ---- store (bf16, 2B scattered; WRITE_SIZE showed no amplification) ----
    #pragma unroll
    for (int mt = 0; mt < 4; ++mt)
        #pragma unroll
        for (int nt = 0; nt < 8; ++nt) {
            size_t rg = row0 + mt * 16 + lq * 4;
            ush* dst = xpc + rg * 512 + w * 128 + nt * 16 + l16;
            #pragma unroll
            for (int q = 0; q < 4; ++q) dst[q * 512] = f2bf(acc[mt][nt][q]);
        }
}

// ---------------- lstm_scan with fused logits+softmax ----------------
__global__ __launch_bounds__(512) void lstm_scan(
    const ush* __restrict__ xpc, const ush* __restrict__ Whp,
    float* __restrict__ c_state, float* __restrict__ out0, float* __restrict__ out1,
    const float* __restrict__ Wy, const float* __restrict__ by, int t0, int t1)
{
    __shared__ ush h_lds[2][16 * 128];
    __shared__ float part[2][4][8][3];
    const int tid = threadIdx.x;
    const int l = tid & 63, w = tid >> 6;
    const int l16 = l & 15, lq = l >> 4;
    const int b0 = blockIdx.x * 4;
    const int jcol = w * 16 + l16;

    short8 whf[4][4];
    #pragma unroll
    for (int g = 0; g < 4; ++g) {
        const ush* bw = Whp + ((size_t)(g * 128 + jcol)) * 128 + lq * 8;
        #pragma unroll
        for (int kf = 0; kf < 4; ++kf) whf[g][kf] = *(const short8*)(bw + kf * 32);
    }
    float wyr0 = Wy[jcol], wyr1 = Wy[128 + jcol], wyr2 = Wy[256 + jcol];
    float by0 = by[0], by1 = by[1], by2 = by[2];

    {   // zero both h buffers (rows 4..15 stay zero)
        ush* hp = &h_lds[0][0];
        for (int idx = tid; idx < 2 * 16 * 128; idx += 512) hp[idx] = 0;
    }
    __syncthreads();

    int cur = 0;
    float c1 = 0.f;
    if (t0 != 0) {
        c1 = c_state[(size_t)(b0 + lq) * 128 + jcol];
        int r = tid >> 7, k = tid & 127;
        float hv = out0[(size_t)(b0 + r) * (270 * 128) + (size_t)(t0 - 1) * 128 + k];
        int off = ((r * 128 + k) * 2) ^ ((r & 7) << 4);
        *(ush*)((char*)(&h_lds[0][0]) + off) = f2bf(hv);
        __syncthreads();
    }

    const ush* xp_base = xpc + ((size_t)(b0 + lq)) * 512 + jcol;
    // prefetch depth 2: Pa holds t, Pb holds t+1; reload consumed set with t+2
    ush Pa[4], Pb[4];
    #pragma unroll
    for (int g = 0; g < 4; ++g) Pa[g] = xp_base[g * 128];
    {
        const ush* pn = xp_base + (size_t)1 * (1024 * 512);
        #pragma unroll
        for (int g = 0; g < 4; ++g) Pb[g] = pn[g * 128];
    }

    auto STEP = [&](int t, ush (&Pu)[4]) {
        short8 afr[4];
        #pragma unroll
        for (int kf = 0; kf < 4; ++kf) {
            int off = ((l16 * 128 + kf * 32 + lq * 8) * 2) ^ ((l16 & 7) << 4);
            afr[kf] = *(const short8*)((const char*)(&h_lds[cur][0]) + off);
        }
        float xg[4];
        #pragma unroll
        for (int g = 0; g < 4; ++g) xg[g] = bf2f(Pu[g]);

        if (t + 2 < t1) {                 // reload freed set for t+2
            const ush* pn = xp_base + (size_t)(t + 2 - t0) * (1024 * 512);
            #pragma unroll
            for (int g = 0; g < 4; ++g) Pu[g] = pn[g * 128];
        }

        // split-K2: two independent chains per gate (depth 2) + add
        f32x4 a0_[4], a1_[4];
        #pragma unroll
        for (int g = 0; g < 4; ++g) {
            a0_[g] = (f32x4){0.f, 0.f, 0.f, 0.f};
            a1_[g] = (f32x4){0.f, 0.f, 0.f, 0.f};
        }
        #pragma unroll
        for (int g = 0; g < 4; ++g) {
            a0_[g] = __builtin_amdgcn_mfma_f32_16x16x32_bf16(afr[0], whf[g][0], a0_[g], 0, 0, 0);
            a1_[g] = __builtin_amdgcn_mfma_f32_16x16x32_bf16(afr[2], whf[g][2], a1_[g], 0, 0, 0);
            a0_[g] = __builtin_amdgcn_mfma_f32_16x16x32_bf16(afr[1], whf[g][1], a0_[g], 0, 0, 0);
            a1_[g] = __builtin_amdgcn_mfma_f32_16x16x32_bf16(afr[3], whf[g][3], a1_[g], 0, 0, 0);
        }

        // redistribute: lane takes reg q=lq from lane l16 -> full-wave gates
        float pre[4];
        #pragma unroll
        for (int g = 0; g < 4; ++g) {
            f32x4 accg = a0_[g] + a1_[g];
            float s0 = __shfl(accg[0], l16);
            float s1 = __shfl(accg[1], l16);
            float s2 = __shfl(accg[2], l16);
            float s3 = __shfl(accg[3], l16);
            float v = (lq == 0) ? s0 : (lq == 1) ? s1 : (lq == 2) ? s2 : s3;
            pre[g] = v + xg[g];
        }
        float fg = sigm_f(pre[0]);
        float ig = sigm_f(pre[1]);
        float gg = tanh_f(pre[2]);
        float og = sigm_f(pre[3]);
        float cn = fg * c1 + ig * gg;
        c1 = cn;
        float hv = og * tanh_f(cn);
        {
            int off = ((lq * 128 + jcol) * 2) ^ ((lq & 7) << 4);
            *(ush*)((char*)(&h_lds[cur ^ 1][0]) + off) = f2bf(hv);
        }
        // fused logits partials over this wave's 16-unit slice
        float p0 = hv * wyr0, p1 = hv * wyr1, p2 = hv * wyr2;
        #pragma unroll
        for (int d = 1; d < 16; d <<= 1) {
            p0 += __shfl_xor(p0, d);
            p1 += __shfl_xor(p1, d);
            p2 += __shfl_xor(p2, d);
        }
        if (l16 == 0) {
            float* pp = &part[t & 1][lq][w][0];
            pp[0] = p0; pp[1] = p1; pp[2] = p2;
        }
        // out0 store: fire-and-forget (never drained by the raw barrier)
        out0[(size_t)(b0 + lq) * (270 * 128) + (size_t)t * 128 + jcol] = hv;

        lds_barrier();

        // softmax finish (reads part[t&1]; next step writes part[(t+1)&1])
        if (tid < 4) {
            const float* pr = &part[t & 1][tid][0][0];
            float L0 = by0, L1 = by1, L2 = by2;
            #pragma unroll
            for (int ww = 0; ww < 8; ++ww) {
                L0 += pr[ww * 3]; L1 += pr[ww * 3 + 1]; L2 += pr[ww * 3 + 2];
            }
            float m = fmaxf(L0, fmaxf(L1, L2));
            float e0 = __expf(L0 - m), e1 = __expf(L1 - m), e2 = __expf(L2 - m);
            float inv = 1.f / (e0 + e1 + e2);
            float* o = out1 + ((size_t)(b0 + tid) * 270 + t) * 3;
            o[0] = e0 * inv; o[1] = e1 * inv; o[2] = e2 * inv;
        }
        cur ^= 1;
    };

    for (int t = t0; t < t1; t += 2) {    // (t1-t0) is always even
        STEP(t, Pa);
        STEP(t + 1, Pb);
    }
    if (t1 != 270)
        c_state[(size_t)(b0 + lq) * 128 + jcol] = c1;
}

// ---------------- host ----------------
extern "C" void kernel_launch(void* const* d_in, const int* in_sizes, int n_in,
                              void* d_out, int out_size, void* d_ws, size_t ws_size,
                              hipStream_t stream) {
    (void)in_sizes; (void)n_in; (void)out_size;
    const float* x   = (const float*)d_in[0];
    const float* Wf  = (const float*)d_in[1];
    const float* Wi  = (const float*)d_in[2];
    const float* Wc  = (const float*)d_in[3];
    const float* Wo  = (const float*)d_in[4];
    const float* Wy  = (const float*)d_in[5];
    const float* bfp = (const float*)d_in[6];
    const float* bip = (const float*)d_in[7];
    const float* bcp = (const float*)d_in[8];
    const float* bop = (const float*)d_in[9];
    const float* byp = (const float*)d_in[10];

    float* out0 = (float*)d_out;                       // [B,T,H]
    float* out1 = out0 + (size_t)1024 * 270 * 128;     // [B,T,3]

    long tc = 6;
    {
        const long cand[6] = {270, 90, 54, 30, 18, 6};
        for (int i = 0; i < 6; ++i) {
            size_t need = (size_t)cand[i] * 1048576u + (2u << 20);
            if (need <= ws_size) { tc = cand[i]; break; }
        }
    }
    char* wsb = (char*)d_ws;
    ush* xpc = (ush*)wsb;                              // tc MB
    char* fx = wsb + (size_t)tc * 1048576u;
    float* c_state = (float*)fx;                       // 512 KB
    ush* Wxp = (ush*)(fx + 524288);                    // 288 KB
    ush* Whp = (ush*)(fx + 524288 + 294912);           // 128 KB
    float* bpk = (float*)(fx + 524288 + 294912 + 131072);

    pack_w<<<576, 256, 0, stream>>>(Wf, Wi, Wc, Wo, bfp, bip, bcp, bop, Wxp, Whp, bpk);

    for (int t0 = 0; t0 < 270; t0 += (int)tc) {
        int Tcur = (270 - t0) < (int)tc ? (270 - t0) : (int)tc;
        int rows = Tcur * 1024;
        xp_gemm<<<rows / 64, 256, 0, stream>>>(x, Wxp, bpk, xpc, t0);
        lstm_scan<<<256, 512, 0, stream>>>(xpc, Whp, c_state, out0, out1, Wy, byp,
                                           t0, t0 + Tcur);
    }
}

// Round 9
// 501.537 us; speedup vs baseline: 1.4057x; 1.2806x over previous
//
#include <hip/hip_runtime.h>
#include <stdint.h>

// LSTM forward, MI355X. H=128, I=270, C=3, B=1024, T=270, NU=512, W rows 398.
//   pack_w (once): Wx->bf16 [512][288] padded, Wh->bf16 [512][128], bias fp32[512]
//   xp_gemm: 64-row x 512-unit tile; x read once; stores xpc as [t][b/16][512u][16b]
//   lstm_scan: 64 blocks x 16 batch rows (M=16 all real -> NO C-redistribute
//     shuffles; gates directly on MFMA C regs). Logits via 4 extra MFMA vs Wy
//     (shifted one step; epilogue covers the last), softmax on 4-lane quads.
// Round-9: bisect of round-8 NaN — clamped activations (NaN-proof, rcp-based),
// all bf16 stores via proven f2bf scalar path; keep structure + new xpc layout.

typedef __attribute__((ext_vector_type(8))) short short8;
typedef __attribute__((ext_vector_type(4))) float f32x4;
typedef __attribute__((ext_vector_type(2))) float f32x2;
typedef __attribute__((ext_vector_type(4))) unsigned int uint4v;
typedef __attribute__((ext_vector_type(2))) unsigned int u32x2;
typedef unsigned short ush;

__device__ __forceinline__ ush f2bf(float f) {
    unsigned u = __float_as_uint(f);
    return (ush)((u + 0x7FFFu + ((u >> 16) & 1u)) >> 16);
}
__device__ __forceinline__ float bf2f(ush s) { return __uint_as_float(((unsigned)s) << 16); }
// Clamped (NaN-laundering) activations; rcp replaces the fp32 divide sequence.
// Clamps guarantee exp() finite and denominators in [1, 1e13] -> rcp well-defined.
__device__ __forceinline__ float sigm_f(float x) {
    x = fminf(fmaxf(x, -30.f), 30.f);
    return __builtin_amdgcn_rcpf(1.f + __expf(-x));
}
__device__ __forceinline__ float tanh_f(float x) {
    x = fminf(fmaxf(x, -15.f), 15.f);
    float e = __expf(-2.f * x);
    return (1.f - e) * __builtin_amdgcn_rcpf(1.f + e);
}
// Raw barrier: LDS visibility only; vmem ops stay outstanding (T4).
__device__ __forceinline__ void lds_barrier() {
    asm volatile("s_waitcnt lgkmcnt(0)" ::: "memory");
    __builtin_amdgcn_s_barrier();
    __builtin_amdgcn_sched_barrier(0);
    asm volatile("" ::: "memory");
}

// ---------------- pack_w ----------------
__global__ __launch_bounds__(256) void pack_w(
    const float* __restrict__ Wf, const float* __restrict__ Wi,
    const float* __restrict__ Wc, const float* __restrict__ Wo,
    const float* __restrict__ bf_, const float* __restrict__ bi_,
    const float* __restrict__ bc_, const float* __restrict__ bo_,
    ush* __restrict__ Wxp, ush* __restrict__ Whp, float* __restrict__ bpk)
{
    int idx = blockIdx.x * 256 + threadIdx.x;
    if (idx < 512 * 288) {
        int u = idx / 288, i = idx - u * 288;
        int g = u >> 7, j = u & 127;
        const float* Wg = (g == 0) ? Wf : (g == 1) ? Wi : (g == 2) ? Wc : Wo;
        float v = (i < 270) ? Wg[(size_t)j * 398 + 128 + i] : 0.f;
        Wxp[idx] = f2bf(v);
    }
    if (idx < 512 * 128) {
        int u = idx >> 7, k = idx & 127;
        int g = u >> 7, j = u & 127;
        const float* Wg = (g == 0) ? Wf : (g == 1) ? Wi : (g == 2) ? Wc : Wo;
        Whp[idx] = f2bf(Wg[(size_t)j * 398 + k]);
    }
    if (idx < 512) {
        int g = idx >> 7, j = idx & 127;
        const float* bg = (g == 0) ? bf_ : (g == 1) ? bi_ : (g == 2) ? bc_ : bo_;
        bpk[idx] = bg[j];
    }
}

// ---------------- xp_gemm: x read once; xpc layout [t][b/16][512u][16b] ----------------
__global__ __launch_bounds__(256, 2) void xp_gemm(
    const float* __restrict__ x, const ush* __restrict__ Wxp,
    const float* __restrict__ bpk, ush* __restrict__ xpc, int t0)
{
    __shared__ ush A_lds[64 * 296];                 // stride 296 elem -> 2-way banks
    const int tid = threadIdx.x;
    const int l = tid & 63, w = tid >> 6;
    const int l16 = l & 15, lq = l >> 4;
    const size_t row0 = (size_t)blockIdx.x * 64;

    // ---- issue all A loads (fp32) ----
    const int srow = tid >> 2, sgrp = tid & 3;      // row 0..63, 8-col group 0..3
    const int r = (int)row0 + srow;
    const int b = r & 1023, tt = (r >> 10) + t0;
    const float* xrow = x + ((size_t)b * 270 + tt) * 270;
    f32x2 stg[9][4];
    #pragma unroll
    for (int ks = 0; ks < 9; ++ks) {
        const int col = ks * 32 + sgrp * 8;
        const float* p = xrow + col;
        if (col + 8 <= 270) {
            stg[ks][0] = *(const f32x2*)p;       stg[ks][1] = *(const f32x2*)(p + 2);
            stg[ks][2] = *(const f32x2*)(p + 4); stg[ks][3] = *(const f32x2*)(p + 6);
        } else {
            float tv[8];
            #pragma unroll
            for (int j = 0; j < 8; ++j) tv[j] = (col + j < 270) ? p[j] : 0.f;
            stg[ks][0] = (f32x2){tv[0], tv[1]}; stg[ks][1] = (f32x2){tv[2], tv[3]};
            stg[ks][2] = (f32x2){tv[4], tv[5]}; stg[ks][3] = (f32x2){tv[6], tv[7]};
        }
    }

    // ---- B-frag base + prefetch ks=0 set; bias ----
    const ush* bptr = Wxp + ((size_t)(w * 128 + l16)) * 288 + lq * 8;
    short8 bA[8], bB[8];
    #pragma unroll
    for (int nt = 0; nt < 8; ++nt) bA[nt] = *(const short8*)(bptr + nt * 4608);
    float bias_v[8];
    #pragma unroll
    for (int nt = 0; nt < 8; ++nt) bias_v[nt] = bpk[w * 128 + nt * 16 + l16];

    // ---- convert + LDS write, one barrier ----
    {
        ush* wrow = &A_lds[srow * 296 + sgrp * 8];
        #pragma unroll
        for (int ks = 0; ks < 9; ++ks) {
            uint4v o;
            #pragma unroll
            for (int p2 = 0; p2 < 4; ++p2) {
                unsigned v;
                asm("v_cvt_pk_bf16_f32 %0, %1, %2"
                    : "=v"(v) : "v"(stg[ks][p2].x), "v"(stg[ks][p2].y));
                o[p2] = v;
            }
            *(uint4v*)(wrow + ks * 32) = o;
        }
    }
    lds_barrier();                                  // bA loads stay in flight

    f32x4 acc[4][8];
    #pragma unroll
    for (int mt = 0; mt < 4; ++mt)
        #pragma unroll
        for (int nt = 0; nt < 8; ++nt)
            acc[mt][nt] = (f32x4){bias_v[nt], bias_v[nt], bias_v[nt], bias_v[nt]};

    // ---- barrier-free K-loop ----
    #pragma unroll
    for (int ks = 0; ks < 9; ++ks) {
        short8* cur = (ks & 1) ? bB : bA;
        short8* nxt = (ks & 1) ? bA : bB;
        if (ks + 1 < 9) {
            const ush* np = bptr + (ks + 1) * 32;
            #pragma unroll
            for (int nt = 0; nt < 8; ++nt) nxt[nt] = *(const short8*)(np + nt * 4608);
        }
        short8 afr[4];
        #pragma unroll
        for (int mt = 0; mt < 4; ++mt)
            afr[mt] = *(const short8*)(&A_lds[(mt * 16 + l16) * 296 + ks * 32 + lq * 8]);
        #pragma unroll
        for (int mt = 0; mt < 4; ++mt)
            #pragma unroll
            for (int nt = 0; nt < 8; ++nt)
                acc[mt][nt] = __builtin_amdgcn_mfma_f32_16x16x32_bf16(
                    afr[mt], cur[nt], acc[mt][nt], 0, 0, 0);
    }

    // ---- store: [t][b/16][512u][16b], proven f2bf scalar path ----
    const int tloc = (int)(row0 >> 10);
    const int bg0 = ((int)row0 & 1023) >> 4;
    #pragma unroll
    for (int mt = 0; mt < 4; ++mt)
        #pragma unroll
        for (int nt = 0; nt < 8; ++nt) {
            int u = w * 128 + nt * 16 + l16;
            ush* dst = xpc + ((size_t)(tloc * 64 + bg0 + mt) * 512 + u) * 16 + lq * 4;
            #pragma unroll
            for (int q = 0; q < 4; ++q) dst[q] = f2bf(acc[mt][nt][q]);
        }
}

// ---------------- lstm_scan: 16 rows/block, no redistribute ----------------
#define STEPB(T, PS)                                                            \
  {                                                                             \
    const int t_ = (T);                                                         \
    short8 afr[4];                                                              \
    _Pragma("unroll") for (int kf = 0; kf < 4; ++kf) {                          \
      int off_ = ((l16 * 128 + kf * 32 + lq * 8) * 2) ^ ((l16 & 7) << 4);       \
      afr[kf] = *(const short8*)((const char*)&h_lds[0][0] + cur * 4096 + off_);\
    }                                                                           \
    f32x4 a0_[4], a1_[4];                                                       \
    _Pragma("unroll") for (int g = 0; g < 4; ++g) {                             \
      a0_[g] = (f32x4){0.f, 0.f, 0.f, 0.f};                                     \
      a1_[g] = (f32x4){0.f, 0.f, 0.f, 0.f};                                     \
    }                                                                           \
    _Pragma("unroll") for (int g = 0; g < 4; ++g) {                             \
      a0_[g] = __builtin_amdgcn_mfma_f32_16x16x32_bf16(afr[0], whf[g][0], a0_[g], 0, 0, 0); \
      a1_[g] = __builtin_amdgcn_mfma_f32_16x16x32_bf16(afr[2], whf[g][2], a1_[g], 0, 0, 0); \
      a0_[g] = __builtin_amdgcn_mfma_f32_16x16x32_bf16(afr[1], whf[g][1], a0_[g], 0, 0, 0); \
      a1_[g] = __builtin_amdgcn_mfma_f32_16x16x32_bf16(afr[3], whf[g][3], a1_[g], 0, 0, 0); \
    }                                                                           \
    f32x4 ay_ = (f32x4){0.f, 0.f, 0.f, 0.f};                                    \
    if (w < 4 && t_ > t0) {   /* logits for t_-1 (afr = h_{t_-1}) */            \
      ay_ = __builtin_amdgcn_mfma_f32_16x16x32_bf16(afr[0], wyf[0], ay_, 0, 0, 0); \
      ay_ = __builtin_amdgcn_mfma_f32_16x16x32_bf16(afr[1], wyf[1], ay_, 0, 0, 0); \
      ay_ = __builtin_amdgcn_mfma_f32_16x16x32_bf16(afr[2], wyf[2], ay_, 0, 0, 0); \
      ay_ = __builtin_amdgcn_mfma_f32_16x16x32_bf16(afr[3], wyf[3], ay_, 0, 0, 0); \
    }                                                                           \
    float xg_[4][4];                                                            \
    _Pragma("unroll") for (int g = 0; g < 4; ++g) {                             \
      u32x2 pv_ = PS[g];                                                        \
      xg_[g][0] = __uint_as_float(pv_.x << 16);                                 \
      xg_[g][1] = __uint_as_float(pv_.x & 0xffff0000u);                         \
      xg_[g][2] = __uint_as_float(pv_.y << 16);                                 \
      xg_[g][3] = __uint_as_float(pv_.y & 0xffff0000u);                         \
    }                                                                           \
    if (t_ + 2 < t1) {                                                          \
      const ush* pn_ = xb + (size_t)(t_ + 2 - t0) * TSTEP;                      \
      _Pragma("unroll") for (int g = 0; g < 4; ++g)                             \
        PS[g] = *(const u32x2*)(pn_ + go[g]);                                   \
    }                                                                           \
    float hv_[4];                                                               \
    _Pragma("unroll") for (int q = 0; q < 4; ++q) {                             \
      float pf_ = a0_[0][q] + a1_[0][q] + xg_[0][q];                            \
      float pi_ = a0_[1][q] + a1_[1][q] + xg_[1][q];                            \
      float pc_ = a0_[2][q] + a1_[2][q] + xg_[2][q];                            \
      float po_ = a0_[3][q] + a1_[3][q] + xg_[3][q];                            \
      float fg_ = sigm_f(pf_);                                                  \
      float ig_ = sigm_f(pi_);                                                  \
      float gg_ = tanh_f(pc_);                                                  \
      float og_ = sigm_f(po_);                                                  \
      float cn_ = fg_ * c[q] + ig_ * gg_;                                       \
      c[q] = cn_;                                                               \
      hv_[q] = og_ * tanh_f(cn_);                                               \
    }                                                                           \
    _Pragma("unroll") for (int q = 0; q < 4; ++q) {                             \
      int rr_ = lq * 4 + q;                                                     \
      int off_ = ((rr_ * 128 + jcol) * 2) ^ ((rr_ & 7) << 4);                   \
      *(ush*)((char*)&h_lds[0][0] + (cur ^ 1) * 4096 + off_) = f2bf(hv_[q]);    \
      out0[(size_t)(b0 + rr_) * (270 * 128) + (size_t)t_ * 128 + jcol] = hv_[q];\
    }                                                                           \
    if (w < 4 && t_ > t0) {                                                     \
      float L_ = ((w == 0) ? ay_[0] : (w == 1) ? ay_[1] : (w == 2) ? ay_[2] : ay_[3]) + byl; \
      if (l16 >= 3) L_ = -1e30f;                                                \
      float m_ = fmaxf(L_, __shfl_xor(L_, 1));                                  \
      m_ = fmaxf(m_, __shfl_xor(m_, 2));                                        \
      float e_ = (l16 < 3) ? __expf(L_ - m_) : 0.f;                             \
      float s_ = e_ + __shfl_xor(e_, 1);                                        \
      s_ = s_ + __shfl_xor(s_, 2);                                              \
      if (l16 < 3)                                                              \
        out1[((size_t)(b0 + lq * 4 + w) * 270 + (t_ - 1)) * 3 + l16] = e_ * __builtin_amdgcn_rcpf(s_); \
    }                                                                           \
    lds_barrier();                                                              \
    cur ^= 1;                                                                   \
  }

__global__ __launch_bounds__(512) void lstm_scan(
    const ush* __restrict__ xpc, const ush* __restrict__ Whp,
    float* __restrict__ c_state, float* __restrict__ out0, float* __restrict__ out1,
    const float* __restrict__ Wy, const float* __restrict__ by, int t0, int t1)
{
    __shared__ ush h_lds[2][16 * 128];
    const int tid = threadIdx.x;
    const int l = tid & 63, w = tid >> 6;
    const int l16 = l & 15, lq = l >> 4;
    const int b0 = blockIdx.x * 16;
    const int jcol = w * 16 + l16;

    short8 whf[4][4];
    #pragma unroll
    for (int g = 0; g < 4; ++g) {
        const ush* bw = Whp + ((size_t)(g * 128 + jcol)) * 128 + lq * 8;
        #pragma unroll
        for (int kf = 0; kf < 4; ++kf) whf[g][kf] = *(const short8*)(bw + kf * 32);
    }
    short8 wyf[4];
    #pragma unroll
    for (int kf = 0; kf < 4; ++kf) {
        short8 fr;
        #pragma unroll
        for (int j = 0; j < 8; ++j)
            fr[j] = (l16 < 3) ? (short)f2bf(Wy[l16 * 128 + kf * 32 + lq * 8 + j]) : (short)0;
        wyf[kf] = fr;
    }
    const float byl = (l16 < 3) ? by[l16] : 0.f;

    {   // zero both h buffers (h_0 = 0)
        ush* hp = &h_lds[0][0];
        for (int idx = tid; idx < 2 * 16 * 128; idx += 512) hp[idx] = 0;
    }
    __syncthreads();

    int cur = 0;
    float c[4] = {0.f, 0.f, 0.f, 0.f};
    if (t0 != 0) {
        #pragma unroll
        for (int q = 0; q < 4; ++q)
            c[q] = c_state[(size_t)(b0 + lq * 4 + q) * 128 + jcol];
        for (int idx = tid; idx < 2048; idx += 512) {
            int rr = idx >> 7, k = idx & 127;
            float hvv = out0[(size_t)(b0 + rr) * (270 * 128) + (size_t)(t0 - 1) * 128 + k];
            int off = ((rr * 128 + k) * 2) ^ ((rr & 7) << 4);
            *(ush*)((char*)&h_lds[0][0] + off) = f2bf(hvv);
        }
        __syncthreads();
    }

    const size_t TSTEP = (size_t)64 * 512 * 16;         // ush per timestep
    const ush* xb = xpc + (size_t)blockIdx.x * 8192;
    int go[4];
    #pragma unroll
    for (int g = 0; g < 4; ++g) go[g] = (g * 128 + jcol) * 16 + lq * 4;

    u32x2 Pa[4], Pb[4];
    #pragma unroll
    for (int g = 0; g < 4; ++g) Pa[g] = *(const u32x2*)(xb + go[g]);
    #pragma unroll
    for (int g = 0; g < 4; ++g) Pb[g] = *(const u32x2*)(xb + TSTEP + go[g]);

    for (int t = t0; t < t1; t += 2) {    // chunk lengths are even
        STEPB(t, Pa)
        STEPB(t + 1, Pb)
    }

    // epilogue: logits/softmax for the last h (t1-1), afr = h_lds[cur]
    {
        short8 afr[4];
        #pragma unroll
        for (int kf = 0; kf < 4; ++kf) {
            int off = ((l16 * 128 + kf * 32 + lq * 8) * 2) ^ ((l16 & 7) << 4);
            afr[kf] = *(const short8*)((const char*)&h_lds[0][0] + cur * 4096 + off);
        }
        if (w < 4) {
            f32x4 ay = (f32x4){0.f, 0.f, 0.f, 0.f};
            ay = __builtin_amdgcn_mfma_f32_16x16x32_bf16(afr[0], wyf[0], ay, 0, 0, 0);
            ay = __builtin_amdgcn_mfma_f32_16x16x32_bf16(afr[1], wyf[1], ay, 0, 0, 0);
            ay = __builtin_amdgcn_mfma_f32_16x16x32_bf16(afr[2], wyf[2], ay, 0, 0, 0);
            ay = __builtin_amdgcn_mfma_f32_16x16x32_bf16(afr[3], wyf[3], ay, 0, 0, 0);
            float L = ((w == 0) ? ay[0] : (w == 1) ? ay[1] : (w == 2) ? ay[2] : ay[3]) + byl;
            if (l16 >= 3) L = -1e30f;
            float m = fmaxf(L, __shfl_xor(L, 1));
            m = fmaxf(m, __shfl_xor(m, 2));
            float e = (l16 < 3) ? __expf(L - m) : 0.f;
            float s = e + __shfl_xor(e, 1);
            s = s + __shfl_xor(s, 2);
            if (l16 < 3)
                out1[((size_t)(b0 + lq * 4 + w) * 270 + (t1 - 1)) * 3 + l16] =
                    e * __builtin_amdgcn_rcpf(s);
        }
    }

    if (t1 != 270) {
        #pragma unroll
        for (int q = 0; q < 4; ++q)
            c_state[(size_t)(b0 + lq * 4 + q) * 128 + jcol] = c[q];
    }
}

// ---------------- host ----------------
extern "C" void kernel_launch(void* const* d_in, const int* in_sizes, int n_in,
                              void* d_out, int out_size, void* d_ws, size_t ws_size,
                              hipStream_t stream) {
    (void)in_sizes; (void)n_in; (void)out_size;
    const float* x   = (const float*)d_in[0];
    const float* Wf  = (const float*)d_in[1];
    const float* Wi  = (const float*)d_in[2];
    const float* Wc  = (const float*)d_in[3];
    const float* Wo  = (const float*)d_in[4];
    const float* Wy  = (const float*)d_in[5];
    const float* bfp = (const float*)d_in[6];
    const float* bip = (const float*)d_in[7];
    const float* bcp = (const float*)d_in[8];
    const float* bop = (const float*)d_in[9];
    const float* byp = (const float*)d_in[10];

    float* out0 = (float*)d_out;                       // [B,T,H]
    float* out1 = out0 + (size_t)1024 * 270 * 128;     // [B,T,3]

    long tc = 6;
    {
        const long cand[6] = {270, 90, 54, 30, 18, 6};
        for (int i = 0; i < 6; ++i) {
            size_t need = (size_t)cand[i] * 1048576u + (2u << 20);
            if (need <= ws_size) { tc = cand[i]; break; }
        }
    }
    char* wsb = (char*)d_ws;
    ush* xpc = (ush*)wsb;                              // tc MB
    char* fx = wsb + (size_t)tc * 1048576u;
    float* c_state = (float*)fx;                       // 512 KB
    ush* Wxp = (ush*)(fx + 524288);                    // 288 KB
    ush* Whp = (ush*)(fx + 524288 + 294912);           // 128 KB
    float* bpk = (float*)(fx + 524288 + 294912 + 131072);

    pack_w<<<576, 256, 0, stream>>>(Wf, Wi, Wc, Wo, bfp, bip, bcp, bop, Wxp, Whp, bpk);

    for (int t0 = 0; t0 < 270; t0 += (int)tc) {
        int Tcur = (270 - t0) < (int)tc ? (270 - t0) : (int)tc;
        int rows = Tcur * 1024;
        xp_gemm<<<rows / 64, 256, 0, stream>>>(x, Wxp, bpk, xpc, t0);
        lstm_scan<<<64, 512, 0, stream>>>(xpc, Whp, c_state, out0, out1, Wy, byp,
                                          t0, t0 + Tcur);
    }
}